// Round 1
// baseline (287.042 us; speedup 1.0000x reference)
//
#include <hip/hip_runtime.h>
#include <hip/hip_bf16.h>

typedef unsigned short ushort_t;
typedef unsigned int u32;
typedef __attribute__((ext_vector_type(8))) short bf16x8;
typedef __attribute__((ext_vector_type(4))) float f32x4;

#define L2E 1.44269504f

__device__ __forceinline__ ushort_t f2bf(float f) {
    union { __hip_bfloat16 b; ushort_t u; } c;
    c.b = __float2bfloat16(f);
    return c.u;
}

__device__ __forceinline__ u32 packbf2(float lo, float hi) {
    return (u32)f2bf(lo) | ((u32)f2bf(hi) << 16);
}

__device__ __forceinline__ f32x4 mfma16(bf16x8 a, bf16x8 b, f32x4 c) {
    return __builtin_amdgcn_mfma_f32_16x16x32_bf16(a, b, c, 0, 0, 0);
}

// ---------------------------------------------------------------------------
// Sizes: B=2, N=2048, DIM=1024, H=16, DH=64.  SCALE=0.125 folded into Wq.
// ws layout (bytes):
//   Xbf   @        0  : 4096*1024 bf16      (8388608)
//   W1bt  @  8388608  : 1152*1024 bf16      (2359296)   rows: 0..1023 Q cols, 1024..1087 K, 1088..1151 V
//   Wobt  @ 10747904  : 1024*1024 bf16      (2097152)   Wobt[j][i] = Wo[i][j]
//   Qb    @ 12845056  : 4096*1024 bf16      (8388608)   Qb[b*2048+n][h*64+e]
//   Kb    @ 21233664  : 2*2048*64 bf16      ( 524288)   Kb[(b*2048+n)*64+e]
//   Vt    @ 21757952  : 2*64*2048 bf16      ( 524288)   Vt[(b*64+e)*2048+n]  (transposed V)
//   Ob    @ 22282240  : 4096*1024 bf16      (8388608)   attention out, [b*2048+n][h*64+e]
// total 30670848 bytes
// ---------------------------------------------------------------------------

__global__ __launch_bounds__(256)
void convert_kernel(const float* __restrict__ x, const float* __restrict__ Wq,
                    const float* __restrict__ Wkv, const float* __restrict__ Wo,
                    ushort_t* __restrict__ Xbf, ushort_t* __restrict__ W1bt,
                    ushort_t* __restrict__ Wobt) {
    int idx = blockIdx.x * 256 + threadIdx.x;
    if (idx < 4194304) { Xbf[idx] = f2bf(x[idx]); return; }
    idx -= 4194304;
    if (idx < 1179648) {
        int c = idx >> 10, d = idx & 1023;
        float v;
        if (c < 1024) v = Wq[((size_t)((c >> 6) * 1024 + d)) * 64 + (c & 63)] * 0.125f;
        else          v = Wkv[(size_t)d * 128 + (c - 1024)];
        W1bt[idx] = f2bf(v);
        return;
    }
    idx -= 1179648;
    if (idx < 1048576) {
        int j = idx >> 10, i = idx & 1023;
        Wobt[idx] = f2bf(Wo[(size_t)i * 1024 + j]);
    }
}

// C[M,N] = A[M,K] @ Bt[N,K]^T, bf16 in, fp32 acc. 128x128 tile, BK=64, 4 waves.
// MODE 0: QKV epilogue (bf16, routed).  MODE 1: fp32 out, ldc=1024.
template <int MODE>
__global__ __launch_bounds__(256)
void gemm128(const ushort_t* __restrict__ A, const ushort_t* __restrict__ Bt,
             ushort_t* __restrict__ Cq, ushort_t* __restrict__ Ck,
             ushort_t* __restrict__ Cv, float* __restrict__ Cf, int K) {
    __shared__ ushort_t As[128][72];
    __shared__ ushort_t Bs[128][72];
    const int tid = threadIdx.x;
    const int lane = tid & 63;
    const int w = tid >> 6;
    const int wm = w >> 1, wn = w & 1;
    const int l15 = lane & 15, g = lane >> 4;
    const int tm = blockIdx.x, tn = blockIdx.y;

    f32x4 acc[4][4];
#pragma unroll
    for (int i = 0; i < 4; i++)
#pragma unroll
        for (int j = 0; j < 4; j++) acc[i][j] = (f32x4)(0.f);

    const int srow = tid >> 3, sseg = tid & 7;
    const ushort_t* Ag = A + ((size_t)(tm * 128 + srow)) * K + sseg * 8;
    const ushort_t* Bg = Bt + ((size_t)(tn * 128 + srow)) * K + sseg * 8;

    bf16x8 ra[4], rb[4];
#pragma unroll
    for (int i = 0; i < 4; i++) {
        ra[i] = *(const bf16x8*)(Ag + (size_t)i * 32 * K);
        rb[i] = *(const bf16x8*)(Bg + (size_t)i * 32 * K);
    }
    const int nk = K >> 6;
    for (int kt = 0; kt < nk; ++kt) {
        __syncthreads();
#pragma unroll
        for (int i = 0; i < 4; i++) {
            *(bf16x8*)&As[srow + i * 32][sseg * 8] = ra[i];
            *(bf16x8*)&Bs[srow + i * 32][sseg * 8] = rb[i];
        }
        __syncthreads();
        if (kt + 1 < nk) {
            const ushort_t* Ag2 = Ag + (kt + 1) * 64;
            const ushort_t* Bg2 = Bg + (kt + 1) * 64;
#pragma unroll
            for (int i = 0; i < 4; i++) {
                ra[i] = *(const bf16x8*)(Ag2 + (size_t)i * 32 * K);
                rb[i] = *(const bf16x8*)(Bg2 + (size_t)i * 32 * K);
            }
        }
#pragma unroll
        for (int kc = 0; kc < 2; kc++) {
            bf16x8 af[4], bfr[4];
#pragma unroll
            for (int mi = 0; mi < 4; mi++)
                af[mi] = *(const bf16x8*)&As[wm * 64 + mi * 16 + l15][kc * 32 + 8 * g];
#pragma unroll
            for (int ni = 0; ni < 4; ni++)
                bfr[ni] = *(const bf16x8*)&Bs[wn * 64 + ni * 16 + l15][kc * 32 + 8 * g];
#pragma unroll
            for (int mi = 0; mi < 4; mi++)
#pragma unroll
                for (int ni = 0; ni < 4; ni++)
                    acc[mi][ni] = mfma16(af[mi], bfr[ni], acc[mi][ni]);
        }
    }
#pragma unroll
    for (int mi = 0; mi < 4; mi++)
#pragma unroll
        for (int ni = 0; ni < 4; ni++)
#pragma unroll
            for (int r = 0; r < 4; r++) {
                int row = tm * 128 + wm * 64 + mi * 16 + 4 * g + r;
                int col = tn * 128 + wn * 64 + ni * 16 + l15;
                float v = acc[mi][ni][r];
                if (MODE == 0) {
                    if (col < 1024)      Cq[(size_t)row * 1024 + col] = f2bf(v);
                    else if (col < 1088) Ck[(size_t)row * 64 + (col - 1024)] = f2bf(v);
                    else                 Cv[((size_t)(row >> 11) * 64 + (col - 1088)) * 2048 + (row & 2047)] = f2bf(v);
                } else {
                    Cf[(size_t)row * 1024 + col] = v;
                }
            }
}

// Flash attention, MQA. 4 waves/block; wave = 16 q-rows; 32-key tiles.
// S^T = K·Q^T via mfma (q lane-local), online softmax, shfl-redistributed P,
// PV from transposed V (contiguous b128 loads). No LDS, no barriers.
__global__ __launch_bounds__(256)
void attn_kernel(const ushort_t* __restrict__ Qb, const ushort_t* __restrict__ Kb,
                 const ushort_t* __restrict__ Vt, ushort_t* __restrict__ Ob,
                 const int* __restrict__ bnds) {
    const int tid = threadIdx.x;
    const int lane = tid & 63;
    const int w = tid >> 6;
    const int l15 = lane & 15, g = lane >> 4;
    const int qt = blockIdx.x;   // 0..31
    const int bh = blockIdx.y;   // 0..31
    const int b = bh >> 4, h = bh & 15;
    const int bnd = bnds[b];
    const int qbase = qt * 64 + w * 16;
    const int qrow = qbase + l15;

    const ushort_t* Qrow = Qb + ((size_t)(b * 2048 + qbase + l15)) * 1024 + h * 64;
    bf16x8 qf0 = *(const bf16x8*)(Qrow + 8 * g);
    bf16x8 qf1 = *(const bf16x8*)(Qrow + 32 + 8 * g);

    f32x4 o[4];
#pragma unroll
    for (int i = 0; i < 4; i++) o[i] = (f32x4)(0.f);
    float m = -1e30f, lsum = 0.f;

    int wl = qbase + 15;
    if (bnd - 1 > wl) wl = bnd - 1;
    if (wl > 2047) wl = 2047;
    const int ntiles = (wl >> 5) + 1;

    const ushort_t* Kbase = Kb + (size_t)b * 2048 * 64;
    const ushort_t* Vbase = Vt + (size_t)b * 64 * 2048;

    for (int kt = 0; kt < ntiles; ++kt) {
        const int ktb = kt * 32;
        const ushort_t* kp0 = Kbase + (size_t)(ktb + l15) * 64 + 8 * g;
        bf16x8 kf00 = *(const bf16x8*)(kp0);
        bf16x8 kf01 = *(const bf16x8*)(kp0 + 32);
        bf16x8 kf10 = *(const bf16x8*)(kp0 + 16 * 64);
        bf16x8 kf11 = *(const bf16x8*)(kp0 + 16 * 64 + 32);
        f32x4 s0 = (f32x4)(0.f), s1 = (f32x4)(0.f);
        s0 = mfma16(kf00, qf0, s0);
        s0 = mfma16(kf01, qf1, s0);
        s1 = mfma16(kf10, qf0, s1);
        s1 = mfma16(kf11, qf1, s1);

        float sv[8];
#pragma unroll
        for (int r = 0; r < 4; r++) { sv[r] = s0[r]; sv[4 + r] = s1[r]; }
        const bool fullvis = (ktb + 31 <= qbase) || (ktb + 31 < bnd);
        if (!fullvis) {
#pragma unroll
            for (int r = 0; r < 4; r++) {
                int key0 = ktb + 4 * g + r;
                if (key0 > qrow && key0 >= bnd) sv[r] = -1e30f;
                int key1 = key0 + 16;
                if (key1 > qrow && key1 >= bnd) sv[4 + r] = -1e30f;
            }
        }
        float tmax = sv[0];
#pragma unroll
        for (int i = 1; i < 8; i++) tmax = fmaxf(tmax, sv[i]);
        tmax = fmaxf(tmax, __shfl_xor(tmax, 16));
        tmax = fmaxf(tmax, __shfl_xor(tmax, 32));
        const float mnew = fmaxf(m, tmax);
        const float alpha = __builtin_amdgcn_exp2f((m - mnew) * L2E);
        float p[8], psum = 0.f;
#pragma unroll
        for (int i = 0; i < 8; i++) {
            p[i] = __builtin_amdgcn_exp2f((sv[i] - mnew) * L2E);
            psum += p[i];
        }
        psum += __shfl_xor(psum, 16);
        psum += __shfl_xor(psum, 32);
        lsum = lsum * alpha + psum;
        m = mnew;

        float alr[4];
#pragma unroll
        for (int r = 0; r < 4; r++) alr[r] = __shfl(alpha, 4 * g + r);
#pragma unroll
        for (int dc = 0; dc < 4; dc++)
#pragma unroll
            for (int r = 0; r < 4; r++) o[dc][r] *= alr[r];

        u32 u0 = packbf2(p[0], p[1]);
        u32 u1 = packbf2(p[2], p[3]);
        u32 u2 = packbf2(p[4], p[5]);
        u32 u3 = packbf2(p[6], p[7]);
        union { u32 u[4]; bf16x8 v; } PU;
#pragma unroll
        for (int j = 0; j < 4; j++) {
            int srcLane = l15 + 16 * (2 * (g & 1) + (j >> 1));
            u32 lo = (u32)__shfl((int)((j & 1) ? u1 : u0), srcLane);
            u32 hi = (u32)__shfl((int)((j & 1) ? u3 : u2), srcLane);
            PU.u[j] = (g < 2) ? lo : hi;
        }
#pragma unroll
        for (int dc = 0; dc < 4; dc++) {
            const ushort_t* vp = Vbase + (size_t)(dc * 16 + l15) * 2048 + ktb + 8 * g;
            bf16x8 vf = *(const bf16x8*)vp;
            o[dc] = mfma16(PU.v, vf, o[dc]);
        }
    }

    float linv[4];
#pragma unroll
    for (int r = 0; r < 4; r++) {
        float lr = __shfl(lsum, 4 * g + r);
        linv[r] = 1.f / lr;
    }
#pragma unroll
    for (int dc = 0; dc < 4; dc++)
#pragma unroll
        for (int r = 0; r < 4; r++) {
            int orow = qbase + 4 * g + r;
            Ob[((size_t)(b * 2048 + orow)) * 1024 + h * 64 + dc * 16 + l15] =
                f2bf(o[dc][r] * linv[r]);
        }
}

extern "C" void kernel_launch(void* const* d_in, const int* in_sizes, int n_in,
                              void* d_out, int out_size, void* d_ws, size_t ws_size,
                              hipStream_t stream) {
    const float* x   = (const float*)d_in[0];
    const float* Wq  = (const float*)d_in[1];
    const float* Wkv = (const float*)d_in[2];
    const float* Wo  = (const float*)d_in[3];
    const int* bnds  = (const int*)d_in[4];
    char* ws = (char*)d_ws;
    ushort_t* Xbf  = (ushort_t*)(ws);
    ushort_t* W1bt = (ushort_t*)(ws + 8388608);
    ushort_t* Wobt = (ushort_t*)(ws + 10747904);
    ushort_t* Qb   = (ushort_t*)(ws + 12845056);
    ushort_t* Kb   = (ushort_t*)(ws + 21233664);
    ushort_t* Vt   = (ushort_t*)(ws + 21757952);
    ushort_t* Ob   = (ushort_t*)(ws + 22282240);
    float* out = (float*)d_out;

    convert_kernel<<<dim3(25088), dim3(256), 0, stream>>>(x, Wq, Wkv, Wo, Xbf, W1bt, Wobt);
    gemm128<0><<<dim3(32, 9), dim3(256), 0, stream>>>(Xbf, W1bt, Qb, Kb, Vt, (float*)nullptr, 1024);
    attn_kernel<<<dim3(32, 32), dim3(256), 0, stream>>>(Qb, Kb, Vt, Ob, bnds);
    gemm128<1><<<dim3(32, 8), dim3(256), 0, stream>>>(Ob, Wobt, (ushort_t*)nullptr,
                                                      (ushort_t*)nullptr, (ushort_t*)nullptr, out, 1024);
}

// Round 2
// 158.763 us; speedup vs baseline: 1.8080x; 1.8080x over previous
//
#include <hip/hip_runtime.h>
#include <hip/hip_bf16.h>

typedef unsigned short ushort_t;
typedef unsigned int u32;
typedef __attribute__((ext_vector_type(8))) short bf16x8;
typedef __attribute__((ext_vector_type(4))) float f32x4;
typedef __attribute__((ext_vector_type(16))) float f32x16;
typedef __attribute__((ext_vector_type(2))) unsigned int u32x2;

#define L2E 1.44269504f

__device__ __forceinline__ ushort_t f2bf(float f) {
    union { __hip_bfloat16 b; ushort_t u; } c;
    c.b = __float2bfloat16(f);
    return c.u;
}

__device__ __forceinline__ f32x4 mfma16(bf16x8 a, bf16x8 b, f32x4 c) {
    return __builtin_amdgcn_mfma_f32_16x16x32_bf16(a, b, c, 0, 0, 0);
}

__device__ __forceinline__ f32x16 mfma32(bf16x8 a, bf16x8 b, f32x16 c) {
    return __builtin_amdgcn_mfma_f32_32x32x16_bf16(a, b, c, 0, 0, 0);
}

// pack 2 f32 -> 2 bf16 in one u32 (RNE)
__device__ __forceinline__ u32 cvtpk(float lo, float hi) {
    u32 r;
    asm("v_cvt_pk_bf16_f32 %0, %1, %2" : "=v"(r) : "v"(lo), "v"(hi));
    return r;
}

// permlane32_swap: returns {D', S'}; D' = {lo: a_own, hi: b_partner}, S' = {lo: a_partner, hi: b_own}
__device__ __forceinline__ u32x2 pl32swap(u32 a, u32 b) {
#if __has_builtin(__builtin_amdgcn_permlane32_swap)
    auto r = __builtin_amdgcn_permlane32_swap((int)a, (int)b, false, false);
    return u32x2{(u32)r[0], (u32)r[1]};
#else
    u32 sa = (u32)__shfl_xor((int)a, 32);
    u32 sb = (u32)__shfl_xor((int)b, 32);
    int lane = threadIdx.x & 63;
    u32 d = (lane >= 32) ? sb : a;
    u32 s = (lane >= 32) ? b : sa;
    return u32x2{d, s};
#endif
}

// value held by lane^32
__device__ __forceinline__ float swap32f(float x, int hi) {
    union { float f; u32 u; } c; c.f = x;
    u32x2 r = pl32swap(c.u, c.u);
    union { u32 u; float f; } o; o.u = hi ? r[0] : r[1];
    return o.f;
}

// ---------------------------------------------------------------------------
// Sizes: B=2, N=2048, DIM=1024, H=16, DH=64.  SCALE=0.125 folded into Wq.
// ws layout (bytes): see R1 comment — unchanged.
// ---------------------------------------------------------------------------

__global__ __launch_bounds__(256)
void convert_kernel(const float* __restrict__ x, const float* __restrict__ Wq,
                    const float* __restrict__ Wkv, const float* __restrict__ Wo,
                    ushort_t* __restrict__ Xbf, ushort_t* __restrict__ W1bt,
                    ushort_t* __restrict__ Wobt) {
    int idx = blockIdx.x * 256 + threadIdx.x;
    if (idx < 4194304) { Xbf[idx] = f2bf(x[idx]); return; }
    idx -= 4194304;
    if (idx < 1179648) {
        int c = idx >> 10, d = idx & 1023;
        float v;
        if (c < 1024) v = Wq[((size_t)((c >> 6) * 1024 + d)) * 64 + (c & 63)] * 0.125f;
        else          v = Wkv[(size_t)d * 128 + (c - 1024)];
        W1bt[idx] = f2bf(v);
        return;
    }
    idx -= 1179648;
    if (idx < 1048576) {
        int j = idx >> 10, i = idx & 1023;
        Wobt[idx] = f2bf(Wo[(size_t)i * 1024 + j]);
    }
}

// C[M,N] = A[M,K] @ Bt[N,K]^T, bf16 in, fp32 acc. 128x128 tile, BK=64, 4 waves.
template <int MODE>
__global__ __launch_bounds__(256)
void gemm128(const ushort_t* __restrict__ A, const ushort_t* __restrict__ Bt,
             ushort_t* __restrict__ Cq, ushort_t* __restrict__ Ck,
             ushort_t* __restrict__ Cv, float* __restrict__ Cf, int K) {
    __shared__ ushort_t As[128][72];
    __shared__ ushort_t Bs[128][72];
    const int tid = threadIdx.x;
    const int lane = tid & 63;
    const int w = tid >> 6;
    const int wm = w >> 1, wn = w & 1;
    const int l15 = lane & 15, g = lane >> 4;
    const int tm = blockIdx.x, tn = blockIdx.y;

    f32x4 acc[4][4];
#pragma unroll
    for (int i = 0; i < 4; i++)
#pragma unroll
        for (int j = 0; j < 4; j++) acc[i][j] = (f32x4)(0.f);

    const int srow = tid >> 3, sseg = tid & 7;
    const ushort_t* Ag = A + ((size_t)(tm * 128 + srow)) * K + sseg * 8;
    const ushort_t* Bg = Bt + ((size_t)(tn * 128 + srow)) * K + sseg * 8;

    bf16x8 ra[4], rb[4];
#pragma unroll
    for (int i = 0; i < 4; i++) {
        ra[i] = *(const bf16x8*)(Ag + (size_t)i * 32 * K);
        rb[i] = *(const bf16x8*)(Bg + (size_t)i * 32 * K);
    }
    const int nk = K >> 6;
    for (int kt = 0; kt < nk; ++kt) {
        __syncthreads();
#pragma unroll
        for (int i = 0; i < 4; i++) {
            *(bf16x8*)&As[srow + i * 32][sseg * 8] = ra[i];
            *(bf16x8*)&Bs[srow + i * 32][sseg * 8] = rb[i];
        }
        __syncthreads();
        if (kt + 1 < nk) {
            const ushort_t* Ag2 = Ag + (kt + 1) * 64;
            const ushort_t* Bg2 = Bg + (kt + 1) * 64;
#pragma unroll
            for (int i = 0; i < 4; i++) {
                ra[i] = *(const bf16x8*)(Ag2 + (size_t)i * 32 * K);
                rb[i] = *(const bf16x8*)(Bg2 + (size_t)i * 32 * K);
            }
        }
#pragma unroll
        for (int kc = 0; kc < 2; kc++) {
            bf16x8 af[4], bfr[4];
#pragma unroll
            for (int mi = 0; mi < 4; mi++)
                af[mi] = *(const bf16x8*)&As[wm * 64 + mi * 16 + l15][kc * 32 + 8 * g];
#pragma unroll
            for (int ni = 0; ni < 4; ni++)
                bfr[ni] = *(const bf16x8*)&Bs[wn * 64 + ni * 16 + l15][kc * 32 + 8 * g];
#pragma unroll
            for (int mi = 0; mi < 4; mi++)
#pragma unroll
                for (int ni = 0; ni < 4; ni++)
                    acc[mi][ni] = mfma16(af[mi], bfr[ni], acc[mi][ni]);
        }
    }
#pragma unroll
    for (int mi = 0; mi < 4; mi++)
#pragma unroll
        for (int ni = 0; ni < 4; ni++)
#pragma unroll
            for (int r = 0; r < 4; r++) {
                int row = tm * 128 + wm * 64 + mi * 16 + 4 * g + r;
                int col = tn * 128 + wn * 64 + ni * 16 + l15;
                float v = acc[mi][ni][r];
                if (MODE == 0) {
                    if (col < 1024)      Cq[(size_t)row * 1024 + col] = f2bf(v);
                    else if (col < 1088) Ck[(size_t)row * 64 + (col - 1024)] = f2bf(v);
                    else                 Cv[((size_t)(row >> 11) * 64 + (col - 1088)) * 2048 + (row & 2047)] = f2bf(v);
                } else {
                    Cf[(size_t)row * 1024 + col] = v;
                }
            }
}

// ---------------------------------------------------------------------------
// Flash attention v2: 32x32 MFMA, swapped QK^T (S^T = K·Q^T), P fully
// lane-local. 4 waves/block, 32 q-rows/wave, KVBLK=64. permlane32_swap for
// all cross-lane traffic; defer-max rescale (THR=8). No LDS, no barriers.
// qt per wave: {bx, 63-bx, 16+bx, 47-bx} -> constant causal work per block.
// ---------------------------------------------------------------------------
__global__ __launch_bounds__(256)
void attn32(const ushort_t* __restrict__ Qb, const ushort_t* __restrict__ Kb,
            const ushort_t* __restrict__ Vt, ushort_t* __restrict__ Ob,
            const int* __restrict__ bnds) {
    const int tid = threadIdx.x;
    const int lane = tid & 63;
    const int w = tid >> 6;
    const int l31 = lane & 31;
    const int hi = lane >> 5;
    const int bx = blockIdx.x;          // 0..15
    const int bh = blockIdx.y;          // 0..31
    const int b = bh >> 4, h = bh & 15;
    const int bnd = bnds[b];
    int qt;
    if (w == 0)      qt = bx;
    else if (w == 1) qt = 63 - bx;
    else if (w == 2) qt = 16 + bx;
    else             qt = 47 - bx;
    const int qbase = qt * 32;
    const int q = qbase + l31;

    // Q fragments (B-operand): lane holds col q=l31, k-rows hi*8+j of each 16-chunk
    const ushort_t* Qp = Qb + ((size_t)(b * 2048 + q)) * 1024 + h * 64 + hi * 8;
    bf16x8 Qf[4];
#pragma unroll
    for (int kk = 0; kk < 4; kk++) Qf[kk] = *(const bf16x8*)(Qp + kk * 16);

    f32x16 oacc0 = (f32x16)(0.f), oacc1 = (f32x16)(0.f);
    float m = -3e38f, lsum = 0.f;

    int wl = qbase + 31;
    if (bnd - 1 > wl) wl = bnd - 1;
    if (wl > 2047) wl = 2047;
    const int niter = (wl >> 6) + 1;

    const ushort_t* Kbase = Kb + (size_t)b * 2048 * 64 + (size_t)l31 * 64 + hi * 8;
    const ushort_t* Vbase = Vt + (size_t)b * 64 * 2048 + (size_t)l31 * 2048 + hi * 8;

    for (int it = 0; it < niter; ++it) {
        const int k0 = it * 64;
        // --- QK^T: S^T[key][q], two 32-key tiles ---
        const ushort_t* kp = Kbase + (size_t)k0 * 64;
        f32x16 s0 = (f32x16)(0.f), s1 = (f32x16)(0.f);
        __builtin_amdgcn_s_setprio(1);
#pragma unroll
        for (int kk = 0; kk < 4; kk++) {
            bf16x8 kf0 = *(const bf16x8*)(kp + kk * 16);
            bf16x8 kf1 = *(const bf16x8*)(kp + 32 * 64 + kk * 16);
            s0 = mfma32(kf0, Qf[kk], s0);
            s1 = mfma32(kf1, Qf[kk], s1);
        }
        __builtin_amdgcn_s_setprio(0);

        float sv[32];
#pragma unroll
        for (int r = 0; r < 16; r++) { sv[r] = s0[r]; sv[16 + r] = s1[r]; }

        // mask: lane's key for reg r (tile t=r>>4, rr=r&15): k0+32t+(rr&3)+8*(rr>>2)+4*hi
        const bool fullvis = (k0 + 63 <= qbase) || (k0 + 63 < bnd);
        if (!fullvis) {
#pragma unroll
            for (int r = 0; r < 32; r++) {
                int rr = r & 15;
                int key = k0 + (r >> 4) * 32 + (rr & 3) + 8 * (rr >> 2) + 4 * hi;
                if (key > q && key >= bnd) sv[r] = -3e38f;
            }
        }

        // --- online softmax (lane-local row; partner lane^32 has other 32 keys) ---
        float tmax = fmaxf(sv[0], sv[1]);
#pragma unroll
        for (int r = 2; r < 32; r++) tmax = fmaxf(tmax, sv[r]);
        tmax = fmaxf(tmax, swap32f(tmax, hi));

        if (!__all(tmax <= m + 8.0f)) {
            float mnew = fmaxf(m, tmax);
            float alpha = __builtin_amdgcn_exp2f((m - mnew) * L2E);
#pragma unroll
            for (int r = 0; r < 16; r++) { oacc0[r] *= alpha; oacc1[r] *= alpha; }
            lsum *= alpha;
            m = mnew;
        }
        const float mL = m * L2E;
        float p[32], psum = 0.f;
#pragma unroll
        for (int r = 0; r < 32; r++) {
            p[r] = __builtin_amdgcn_exp2f(sv[r] * L2E - mL);
            psum += p[r];
        }
        psum += swap32f(psum, hi);
        lsum += psum;

        // --- P pack (cvt_pk + permlane32_swap) and PV per 16-key chunk ---
        const ushort_t* vp = Vbase + k0;
        __builtin_amdgcn_s_setprio(1);
#pragma unroll
        for (int c = 0; c < 4; c++) {
            const float* pc = &p[c * 8];
            u32 a0 = cvtpk(pc[0], pc[1]);   // lo:(k0,k1)  hi:(k4,k5)
            u32 b0 = cvtpk(pc[4], pc[5]);   // lo:(k8,k9)  hi:(k12,k13)
            u32 c0 = cvtpk(pc[2], pc[3]);
            u32 d0 = cvtpk(pc[6], pc[7]);
            u32x2 r02 = pl32swap(a0, b0);   // -> words 0, 2
            u32x2 r13 = pl32swap(c0, d0);   // -> words 1, 3
            union { u32 u[4]; bf16x8 v; } P;
            P.u[0] = r02[0]; P.u[1] = r13[0]; P.u[2] = r02[1]; P.u[3] = r13[1];
            bf16x8 vf0 = *(const bf16x8*)(vp + c * 16);
            bf16x8 vf1 = *(const bf16x8*)(vp + (size_t)32 * 2048 + c * 16);
            oacc0 = mfma32(vf0, P.v, oacc0);
            oacc1 = mfma32(vf1, P.v, oacc1);
        }
        __builtin_amdgcn_s_setprio(0);
    }

    const float li = 1.f / lsum;
    ushort_t* Op = Ob + ((size_t)(b * 2048 + q)) * 1024 + h * 64;
#pragma unroll
    for (int dh = 0; dh < 2; dh++)
#pragma unroll
        for (int rq = 0; rq < 4; rq++) {
            union { ushort_t s[4]; u32x2 u; } st;
#pragma unroll
            for (int j = 0; j < 4; j++) {
                float v = (dh == 0 ? oacc0[4 * rq + j] : oacc1[4 * rq + j]) * li;
                st.s[j] = f2bf(v);
            }
            int d0 = dh * 32 + 8 * rq + 4 * hi;
            *(u32x2*)(Op + d0) = st.u;
        }
}

extern "C" void kernel_launch(void* const* d_in, const int* in_sizes, int n_in,
                              void* d_out, int out_size, void* d_ws, size_t ws_size,
                              hipStream_t stream) {
    const float* x   = (const float*)d_in[0];
    const float* Wq  = (const float*)d_in[1];
    const float* Wkv = (const float*)d_in[2];
    const float* Wo  = (const float*)d_in[3];
    const int* bnds  = (const int*)d_in[4];
    char* ws = (char*)d_ws;
    ushort_t* Xbf  = (ushort_t*)(ws);
    ushort_t* W1bt = (ushort_t*)(ws + 8388608);
    ushort_t* Wobt = (ushort_t*)(ws + 10747904);
    ushort_t* Qb   = (ushort_t*)(ws + 12845056);
    ushort_t* Kb   = (ushort_t*)(ws + 21233664);
    ushort_t* Vt   = (ushort_t*)(ws + 21757952);
    ushort_t* Ob   = (ushort_t*)(ws + 22282240);
    float* out = (float*)d_out;

    convert_kernel<<<dim3(25088), dim3(256), 0, stream>>>(x, Wq, Wkv, Wo, Xbf, W1bt, Wobt);
    gemm128<0><<<dim3(32, 9), dim3(256), 0, stream>>>(Xbf, W1bt, Qb, Kb, Vt, (float*)nullptr, 1024);
    attn32<<<dim3(16, 32), dim3(256), 0, stream>>>(Qb, Kb, Vt, Ob, bnds);
    gemm128<1><<<dim3(32, 8), dim3(256), 0, stream>>>(Ob, Wobt, (ushort_t*)nullptr,
                                                      (ushort_t*)nullptr, (ushort_t*)nullptr, out, 1024);
}

// Round 3
// 155.149 us; speedup vs baseline: 1.8501x; 1.0233x over previous
//
#include <hip/hip_runtime.h>
#include <hip/hip_bf16.h>

typedef unsigned short ushort_t;
typedef unsigned int u32;
typedef __attribute__((ext_vector_type(8))) short bf16x8;
typedef __attribute__((ext_vector_type(4))) float f32x4;
typedef __attribute__((ext_vector_type(16))) float f32x16;
typedef __attribute__((ext_vector_type(2))) unsigned int u32x2;

#define L2E 1.44269504f

__device__ __forceinline__ ushort_t f2bf(float f) {
    union { __hip_bfloat16 b; ushort_t u; } c;
    c.b = __float2bfloat16(f);
    return c.u;
}

__device__ __forceinline__ f32x4 mfma16(bf16x8 a, bf16x8 b, f32x4 c) {
    return __builtin_amdgcn_mfma_f32_16x16x32_bf16(a, b, c, 0, 0, 0);
}

__device__ __forceinline__ f32x16 mfma32(bf16x8 a, bf16x8 b, f32x16 c) {
    return __builtin_amdgcn_mfma_f32_32x32x16_bf16(a, b, c, 0, 0, 0);
}

// pack 2 f32 -> 2 bf16 in one u32 (RNE)
__device__ __forceinline__ u32 cvtpk(float lo, float hi) {
    u32 r;
    asm("v_cvt_pk_bf16_f32 %0, %1, %2" : "=v"(r) : "v"(lo), "v"(hi));
    return r;
}

__device__ __forceinline__ u32x2 pl32swap(u32 a, u32 b) {
#if __has_builtin(__builtin_amdgcn_permlane32_swap)
    auto r = __builtin_amdgcn_permlane32_swap((int)a, (int)b, false, false);
    return u32x2{(u32)r[0], (u32)r[1]};
#else
    u32 sa = (u32)__shfl_xor((int)a, 32);
    u32 sb = (u32)__shfl_xor((int)b, 32);
    int lane = threadIdx.x & 63;
    u32 d = (lane >= 32) ? sb : a;
    u32 s = (lane >= 32) ? b : sa;
    return u32x2{d, s};
#endif
}

// value held by lane^32
__device__ __forceinline__ float swap32f(float x, int hi) {
    union { float f; u32 u; } c; c.f = x;
    u32x2 r = pl32swap(c.u, c.u);
    union { u32 u; float f; } o; o.u = hi ? r[0] : r[1];
    return o.f;
}

// ---------------------------------------------------------------------------
// Sizes: B=2, N=2048, DIM=1024, H=16, DH=64.  SCALE=0.125 folded into Wq.
// ws layout (bytes): see earlier round comment — unchanged.
// ---------------------------------------------------------------------------

__global__ __launch_bounds__(256)
void convert_kernel(const float* __restrict__ x, const float* __restrict__ Wq,
                    const float* __restrict__ Wkv, const float* __restrict__ Wo,
                    ushort_t* __restrict__ Xbf, ushort_t* __restrict__ W1bt,
                    ushort_t* __restrict__ Wobt) {
    int idx = blockIdx.x * 256 + threadIdx.x;
    if (idx < 4194304) { Xbf[idx] = f2bf(x[idx]); return; }
    idx -= 4194304;
    if (idx < 1179648) {
        int c = idx >> 10, d = idx & 1023;
        float v;
        if (c < 1024) v = Wq[((size_t)((c >> 6) * 1024 + d)) * 64 + (c & 63)] * 0.125f;
        else          v = Wkv[(size_t)d * 128 + (c - 1024)];
        W1bt[idx] = f2bf(v);
        return;
    }
    idx -= 1179648;
    if (idx < 1048576) {
        int j = idx >> 10, i = idx & 1023;
        Wobt[idx] = f2bf(Wo[(size_t)i * 1024 + j]);
    }
}

// C[M,N] = A[M,K] @ Bt[N,K]^T, bf16 in, fp32 acc. 128x128 tile, BK=64, 4 waves.
template <int MODE>
__global__ __launch_bounds__(256)
void gemm128(const ushort_t* __restrict__ A, const ushort_t* __restrict__ Bt,
             ushort_t* __restrict__ Cq, ushort_t* __restrict__ Ck,
             ushort_t* __restrict__ Cv, float* __restrict__ Cf, int K) {
    __shared__ ushort_t As[128][72];
    __shared__ ushort_t Bs[128][72];
    const int tid = threadIdx.x;
    const int lane = tid & 63;
    const int w = tid >> 6;
    const int wm = w >> 1, wn = w & 1;
    const int l15 = lane & 15, g = lane >> 4;
    const int tm = blockIdx.x, tn = blockIdx.y;

    f32x4 acc[4][4];
#pragma unroll
    for (int i = 0; i < 4; i++)
#pragma unroll
        for (int j = 0; j < 4; j++) acc[i][j] = (f32x4)(0.f);

    const int srow = tid >> 3, sseg = tid & 7;
    const ushort_t* Ag = A + ((size_t)(tm * 128 + srow)) * K + sseg * 8;
    const ushort_t* Bg = Bt + ((size_t)(tn * 128 + srow)) * K + sseg * 8;

    bf16x8 ra[4], rb[4];
#pragma unroll
    for (int i = 0; i < 4; i++) {
        ra[i] = *(const bf16x8*)(Ag + (size_t)i * 32 * K);
        rb[i] = *(const bf16x8*)(Bg + (size_t)i * 32 * K);
    }
    const int nk = K >> 6;
    for (int kt = 0; kt < nk; ++kt) {
        __syncthreads();
#pragma unroll
        for (int i = 0; i < 4; i++) {
            *(bf16x8*)&As[srow + i * 32][sseg * 8] = ra[i];
            *(bf16x8*)&Bs[srow + i * 32][sseg * 8] = rb[i];
        }
        __syncthreads();
        if (kt + 1 < nk) {
            const ushort_t* Ag2 = Ag + (kt + 1) * 64;
            const ushort_t* Bg2 = Bg + (kt + 1) * 64;
#pragma unroll
            for (int i = 0; i < 4; i++) {
                ra[i] = *(const bf16x8*)(Ag2 + (size_t)i * 32 * K);
                rb[i] = *(const bf16x8*)(Bg2 + (size_t)i * 32 * K);
            }
        }
#pragma unroll
        for (int kc = 0; kc < 2; kc++) {
            bf16x8 af[4], bfr[4];
#pragma unroll
            for (int mi = 0; mi < 4; mi++)
                af[mi] = *(const bf16x8*)&As[wm * 64 + mi * 16 + l15][kc * 32 + 8 * g];
#pragma unroll
            for (int ni = 0; ni < 4; ni++)
                bfr[ni] = *(const bf16x8*)&Bs[wn * 64 + ni * 16 + l15][kc * 32 + 8 * g];
#pragma unroll
            for (int mi = 0; mi < 4; mi++)
#pragma unroll
                for (int ni = 0; ni < 4; ni++)
                    acc[mi][ni] = mfma16(af[mi], bfr[ni], acc[mi][ni]);
        }
    }
#pragma unroll
    for (int mi = 0; mi < 4; mi++)
#pragma unroll
        for (int ni = 0; ni < 4; ni++)
#pragma unroll
            for (int r = 0; r < 4; r++) {
                int row = tm * 128 + wm * 64 + mi * 16 + 4 * g + r;
                int col = tn * 128 + wn * 64 + ni * 16 + l15;
                float v = acc[mi][ni][r];
                if (MODE == 0) {
                    if (col < 1024)      Cq[(size_t)row * 1024 + col] = f2bf(v);
                    else if (col < 1088) Ck[(size_t)row * 64 + (col - 1024)] = f2bf(v);
                    else                 Cv[((size_t)(row >> 11) * 64 + (col - 1088)) * 2048 + (row & 2047)] = f2bf(v);
                } else {
                    Cf[(size_t)row * 1024 + col] = v;
                }
            }
}

// ---------------------------------------------------------------------------
// Flash attention v3: like v2 but spill-free — masking in place on f32x16 S,
// P processed in 8-value chunks (exp2 -> cvt_pk -> permlane -> 2 MFMA), lsum
// kept as per-lane partial. launch_bounds(256,2): grid gives 2 waves/SIMD,
// so allow up to 256 VGPR (R2's 84-VGPR allocation spilled sv[32]/p[32]).
// ---------------------------------------------------------------------------
__global__ __launch_bounds__(256, 2)
void attn32(const ushort_t* __restrict__ Qb, const ushort_t* __restrict__ Kb,
            const ushort_t* __restrict__ Vt, ushort_t* __restrict__ Ob,
            const int* __restrict__ bnds) {
    const int tid = threadIdx.x;
    const int lane = tid & 63;
    const int w = tid >> 6;
    const int l31 = lane & 31;
    const int hi = lane >> 5;
    const int bx = blockIdx.x;          // 0..15
    const int bh = blockIdx.y;          // 0..31
    const int b = bh >> 4, h = bh & 15;
    const int bnd = bnds[b];
    int qt;
    if (w == 0)      qt = bx;
    else if (w == 1) qt = 63 - bx;
    else if (w == 2) qt = 16 + bx;
    else             qt = 47 - bx;
    const int qbase = qt * 32;
    const int q = qbase + l31;

    const ushort_t* Qp = Qb + ((size_t)(b * 2048 + q)) * 1024 + h * 64 + hi * 8;
    bf16x8 Qf[4];
#pragma unroll
    for (int kk = 0; kk < 4; kk++) Qf[kk] = *(const bf16x8*)(Qp + kk * 16);

    f32x16 oacc0 = (f32x16)(0.f), oacc1 = (f32x16)(0.f);
    float m = -3e38f, lsum = 0.f;   // lsum: partial over this lane's 32 keys

    int wl = qbase + 31;
    if (bnd - 1 > wl) wl = bnd - 1;
    if (wl > 2047) wl = 2047;
    const int niter = (wl >> 6) + 1;

    const ushort_t* Kbase = Kb + (size_t)b * 2048 * 64 + (size_t)l31 * 64 + hi * 8;
    const ushort_t* Vbase = Vt + (size_t)b * 64 * 2048 + (size_t)l31 * 2048 + hi * 8;

    for (int it = 0; it < niter; ++it) {
        const int k0 = it * 64;
        const ushort_t* kp = Kbase + (size_t)k0 * 64;
        bf16x8 kf[8];
#pragma unroll
        for (int kk = 0; kk < 4; kk++) {
            kf[kk]     = *(const bf16x8*)(kp + kk * 16);
            kf[4 + kk] = *(const bf16x8*)(kp + 32 * 64 + kk * 16);
        }
        f32x16 s0 = (f32x16)(0.f), s1 = (f32x16)(0.f);
        __builtin_amdgcn_s_setprio(1);
#pragma unroll
        for (int kk = 0; kk < 4; kk++) {
            s0 = mfma32(kf[kk], Qf[kk], s0);
            s1 = mfma32(kf[4 + kk], Qf[kk], s1);
        }
        __builtin_amdgcn_s_setprio(0);

        // prefetch V fragments (L2 latency hides under softmax VALU chain)
        const ushort_t* vp = Vbase + k0;
        bf16x8 vf[8];
#pragma unroll
        for (int c = 0; c < 4; c++) {
            vf[c]     = *(const bf16x8*)(vp + c * 16);
            vf[4 + c] = *(const bf16x8*)(vp + (size_t)32 * 2048 + c * 16);
        }

        // mask in place; reg r of tile t holds key k0+32t+(r&3)+8*(r>>2)+4*hi
        const bool fullvis = (k0 + 63 <= qbase) || (k0 + 63 < bnd);
        if (!fullvis) {
#pragma unroll
            for (int r = 0; r < 16; r++) {
                int key0 = k0 + (r & 3) + 8 * (r >> 2) + 4 * hi;
                if (key0 > q && key0 >= bnd) s0[r] = -3e38f;
                int key1 = key0 + 32;
                if (key1 > q && key1 >= bnd) s1[r] = -3e38f;
            }
        }

        // row max (lane-local 32 + partner swap)
        float tmax = fmaxf(s0[0], s0[1]);
#pragma unroll
        for (int r = 2; r < 16; r++) tmax = fmaxf(tmax, s0[r]);
#pragma unroll
        for (int r = 0; r < 16; r++) tmax = fmaxf(tmax, s1[r]);
        tmax = fmaxf(tmax, swap32f(tmax, hi));

        if (!__all(tmax <= m + 8.0f)) {
            float mnew = fmaxf(m, tmax);
            float alpha = __builtin_amdgcn_exp2f((m - mnew) * L2E);
#pragma unroll
            for (int r = 0; r < 16; r++) { oacc0[r] *= alpha; oacc1[r] *= alpha; }
            lsum *= alpha;
            m = mnew;
        }
        const float mL = m * L2E;

        // P chunks: c0=s0[0..7], c1=s0[8..15], c2=s1[0..7], c3=s1[8..15]
        __builtin_amdgcn_s_setprio(1);
#pragma unroll
        for (int c = 0; c < 4; c++) {
            float p0, p1, p2, p3, p4, p5, p6, p7;
            {
                const f32x16& sc = (c < 2) ? s0 : s1;
                const int base = (c & 1) * 8;
                p0 = __builtin_amdgcn_exp2f(sc[base + 0] * L2E - mL);
                p1 = __builtin_amdgcn_exp2f(sc[base + 1] * L2E - mL);
                p2 = __builtin_amdgcn_exp2f(sc[base + 2] * L2E - mL);
                p3 = __builtin_amdgcn_exp2f(sc[base + 3] * L2E - mL);
                p4 = __builtin_amdgcn_exp2f(sc[base + 4] * L2E - mL);
                p5 = __builtin_amdgcn_exp2f(sc[base + 5] * L2E - mL);
                p6 = __builtin_amdgcn_exp2f(sc[base + 6] * L2E - mL);
                p7 = __builtin_amdgcn_exp2f(sc[base + 7] * L2E - mL);
            }
            lsum += ((p0 + p1) + (p2 + p3)) + ((p4 + p5) + (p6 + p7));
            u32 a0 = cvtpk(p0, p1);
            u32 c0 = cvtpk(p2, p3);
            u32 b0 = cvtpk(p4, p5);
            u32 d0 = cvtpk(p6, p7);
            u32x2 r02 = pl32swap(a0, b0);
            u32x2 r13 = pl32swap(c0, d0);
            union { u32 u[4]; bf16x8 v; } P;
            P.u[0] = r02[0]; P.u[1] = r13[0]; P.u[2] = r02[1]; P.u[3] = r13[1];
            oacc0 = mfma32(vf[c], P.v, oacc0);
            oacc1 = mfma32(vf[4 + c], P.v, oacc1);
        }
        __builtin_amdgcn_s_setprio(0);
    }

    const float ltot = lsum + swap32f(lsum, hi);
    const float li = 1.f / ltot;
    ushort_t* Op = Ob + ((size_t)(b * 2048 + q)) * 1024 + h * 64;
#pragma unroll
    for (int dh = 0; dh < 2; dh++)
#pragma unroll
        for (int rq = 0; rq < 4; rq++) {
            union { ushort_t s[4]; u32x2 u; } st;
#pragma unroll
            for (int j = 0; j < 4; j++) {
                float v = (dh == 0 ? oacc0[4 * rq + j] : oacc1[4 * rq + j]) * li;
                st.s[j] = f2bf(v);
            }
            int d0 = dh * 32 + 8 * rq + 4 * hi;
            *(u32x2*)(Op + d0) = st.u;
        }
}

extern "C" void kernel_launch(void* const* d_in, const int* in_sizes, int n_in,
                              void* d_out, int out_size, void* d_ws, size_t ws_size,
                              hipStream_t stream) {
    const float* x   = (const float*)d_in[0];
    const float* Wq  = (const float*)d_in[1];
    const float* Wkv = (const float*)d_in[2];
    const float* Wo  = (const float*)d_in[3];
    const int* bnds  = (const int*)d_in[4];
    char* ws = (char*)d_ws;
    ushort_t* Xbf  = (ushort_t*)(ws);
    ushort_t* W1bt = (ushort_t*)(ws + 8388608);
    ushort_t* Wobt = (ushort_t*)(ws + 10747904);
    ushort_t* Qb   = (ushort_t*)(ws + 12845056);
    ushort_t* Kb   = (ushort_t*)(ws + 21233664);
    ushort_t* Vt   = (ushort_t*)(ws + 21757952);
    ushort_t* Ob   = (ushort_t*)(ws + 22282240);
    float* out = (float*)d_out;

    convert_kernel<<<dim3(25088), dim3(256), 0, stream>>>(x, Wq, Wkv, Wo, Xbf, W1bt, Wobt);
    gemm128<0><<<dim3(32, 9), dim3(256), 0, stream>>>(Xbf, W1bt, Qb, Kb, Vt, (float*)nullptr, 1024);
    attn32<<<dim3(16, 32), dim3(256), 0, stream>>>(Qb, Kb, Vt, Ob, bnds);
    gemm128<1><<<dim3(32, 8), dim3(256), 0, stream>>>(Ob, Wobt, (ushort_t*)nullptr,
                                                      (ushort_t*)nullptr, (ushort_t*)nullptr, out, 1024);
}